// Round 2
// baseline (12016.183 us; speedup 1.0000x reference)
//
#include <hip/hip_runtime.h>
#include <hip/hip_cooperative_groups.h>

namespace cg = cooperative_groups;

typedef unsigned short u16;
typedef __attribute__((ext_vector_type(8))) short bf16x8;
typedef __attribute__((ext_vector_type(4))) float f32x4;

#define NB 128
#define NOBJ 36
#define VDIM 2048
#define EMB 1024
#define HID 1024
#define NTOK 10000
#define MAXLEN 20
#define T_STEPS 19
#define PRED_STRIDE (MAXLEN * NTOK)          /* 200000 */
#define ALPHA_OFF ((long)NB * MAXLEN * NTOK) /* 25,600,000 */
#define HSZ (NB * HID)                       /* 131072 */

struct Args {
  const float *v, *caption;
  const int *cap_len;
  const float *Wih1, *Whh1, *bih1, *bhh1, *Wih2, *Whh2, *bih2, *bhh2;
  const float *Wv, *bv, *Wq, *bq, *wa, *ba, *W1, *b1, *W2, *b2;
  float *out;
  int *order, *dl;
  // bf16 conversions of weights/inputs (built in P0 every launch)
  u16 *Wih1h, *Whh1h, *Wih2h, *Whh2h, *Wvh, *Wqh, *W1h, *W2h, *vh, *caph, *capl;
  u16 *vproj16;
  float *gv1, *gh2s, *h1f, *h2f, *qf;
  u16 *h1hi, *h1lo, *h2hi, *h2lo, *hqhi, *hqlo, *avhi, *avlo, *vmhi, *vmlo;
};

__device__ inline float b2f(u16 h) {
  unsigned u = ((unsigned)h) << 16;
  float f;
  __builtin_memcpy(&f, &u, 4);
  return f;
}
__device__ inline u16 f2b_trunc(float x) {
  unsigned u;
  __builtin_memcpy(&u, &x, 4);
  return (u16)(u >> 16);
}
__device__ inline u16 f2b_rne(float x) {
  unsigned u;
  __builtin_memcpy(&u, &x, 4);
  unsigned r = (u + 0x7fffu + ((u >> 16) & 1u)) >> 16;
  return (u16)r;
}
__device__ inline void split_bf16(float x, u16 &hi, u16 &lo) {
  hi = f2b_trunc(x);
  lo = f2b_trunc(x - b2f(hi));
}
__device__ inline bf16x8 ldb8(const u16 *p) {
  uint4 u = *(const uint4 *)p;
  bf16x8 v;
  __builtin_memcpy(&v, &u, 16);
  return v;
}
__device__ inline f32x4 mfma16(bf16x8 a, bf16x8 b, f32x4 c) {
  return __builtin_amdgcn_mfma_f32_16x16x32_bf16(a, b, c, 0, 0, 0);
}
__device__ inline float sigmoidf_(float x) {
  float e = __expf(-fabsf(x));
  float p = 1.f / (1.f + e);
  return x >= 0.f ? p : 1.f - p;
}
__device__ inline float tanhf_(float x) {
  float e = __expf(-2.f * fabsf(x));
  float t = (1.f - e) / (1.f + e);
  return x >= 0.f ? t : -t;
}
__device__ inline float wred_sum(float x) {
#pragma unroll
  for (int off = 32; off > 0; off >>= 1) x += __shfl_xor(x, off, 64);
  return x;
}
__device__ inline float wred_max(float x) {
#pragma unroll
  for (int off = 32; off > 0; off >>= 1) x = fmaxf(x, __shfl_xor(x, off, 64));
  return x;
}

// f32 -> bf16(RNE), grid-strided, float4/ushort4 vectorized (n % 4 == 0)
__device__ inline void cvt_hi(const float *src, u16 *dst, long n, long g0,
                              long gs) {
  for (long i = g0 * 4; i < n; i += gs * 4) {
    float4 f = *(const float4 *)(src + i);
    ushort4 o;
    o.x = f2b_rne(f.x);
    o.y = f2b_rne(f.y);
    o.z = f2b_rne(f.z);
    o.w = f2b_rne(f.w);
    *(ushort4 *)(dst + i) = o;
  }
}
// f32 -> hi(trunc) + lo(residual) split
__device__ inline void cvt_split(const float *src, u16 *dhi, u16 *dlo, long n,
                                 long g0, long gs) {
  for (long i = g0 * 4; i < n; i += gs * 4) {
    float4 f = *(const float4 *)(src + i);
    ushort4 h, l;
    split_bf16(f.x, h.x, l.x);
    split_bf16(f.y, h.y, l.y);
    split_bf16(f.z, h.z, l.z);
    split_bf16(f.w, h.w, l.w);
    *(ushort4 *)(dhi + i) = h;
    *(ushort4 *)(dlo + i) = l;
  }
}

// Per-wave K-loop: acc[i] += X(hi[+lo]) @ W-rows(i-th tile, stride wstride).
// A-frag: lane holds A[m=lane&15][k=quad*8+j]; B-frag: W[n=lane&15][same k].
template <int NT, bool SPLIT>
__device__ inline void mmk(f32x4 *acc, const u16 *ah, const u16 *al,
                           const u16 *wr, long wstride, int ksteps) {
  for (int ks = 0; ks < ksteps; ++ks) {
    const int ko = ks * 32;
    bf16x8 va = ldb8(ah + ko);
    bf16x8 vl;
    if constexpr (SPLIT) vl = ldb8(al + ko);
#pragma unroll
    for (int i = 0; i < NT; ++i) {
      bf16x8 vb = ldb8(wr + (long)i * wstride + ko);
      acc[i] = mfma16(va, vb, acc[i]);
      if constexpr (SPLIT) acc[i] = mfma16(vl, vb, acc[i]);
    }
  }
}

__global__ void __launch_bounds__(512) butd(Args a) {
  cg::grid_group grid = cg::this_grid();
  const int tid = threadIdx.x;
  const int blk = blockIdx.x;
  const int lane = tid & 63;
  const int wv = tid >> 6; // 0..7
  const int m = lane & 15;
  const int quad = lane >> 4;
  __shared__ float sl[64];

  const long gs = 256L * 512;
  const long g0 = (long)blk * 512 + tid;

  //================= P0: weight/input conversion + argsort + zero-init ======
  cvt_hi(a.Wih1, a.Wih1h, 3072L * 4096, g0, gs);
  cvt_hi(a.Whh1, a.Whh1h, 3072L * 1024, g0, gs);
  cvt_hi(a.Wih2, a.Wih2h, 3072L * 3072, g0, gs);
  cvt_hi(a.Whh2, a.Whh2h, 3072L * 1024, g0, gs);
  cvt_hi(a.Wv, a.Wvh, 1024L * 2048, g0, gs);
  cvt_hi(a.Wq, a.Wqh, 1024L * 1024, g0, gs);
  cvt_hi(a.W1, a.W1h, 1024L * 1024, g0, gs);
  cvt_hi(a.W2, a.W2h, (long)NTOK * 1024, g0, gs);
  cvt_hi(a.v, a.vh, (long)NB * NOBJ * VDIM, g0, gs);
  cvt_split(a.caption, a.caph, a.capl, (long)NB * MAXLEN * EMB, g0, gs);

  if (blk == 0 && tid < NB) {
    int ki = a.cap_len[tid];
    int rank = 0;
    for (int j = 0; j < NB; ++j) {
      int kj = a.cap_len[j];
      rank += (kj > ki) || (kj == ki && j < tid);
    }
    a.order[rank] = tid;
    a.dl[rank] = ki - 1;
  }
  for (long i = g0; i < (long)NB * NTOK; i += gs) {
    long b = i / NTOK, n = i - b * NTOK;
    a.out[b * PRED_STRIDE + (long)(MAXLEN - 1) * NTOK + n] = 0.f;
  }
  for (long i = g0; i < (long)NB * NOBJ; i += gs) {
    long b = i / NOBJ, n = i - b * NOBJ;
    a.out[ALPHA_OFF + b * (MAXLEN * NOBJ) + (MAXLEN - 1) * NOBJ + n] = 0.f;
  }
  for (long i = g0; i < HSZ; i += gs) { // zero buffer 0 of states
    a.h1f[i] = 0.f;
    a.h2f[i] = 0.f;
    a.h1hi[i] = 0;
    a.h1lo[i] = 0;
    a.h2hi[i] = 0;
    a.h2lo[i] = 0;
  }
  grid.sync();

  //================= P1: v_mean (exact f32, split) + vproj GEMM =============
  if (blk < NB) {
    const int b = blk;
    const int ob = a.order[b];
    const float *vb = a.v + (long)ob * NOBJ * VDIM;
    for (int d = tid; d < VDIM; d += 512) {
      float s = 0.f;
      for (int k = 0; k < NOBJ; ++k) s += vb[(long)k * VDIM + d];
      s *= (1.f / 36.f);
      u16 hi, lo;
      split_bf16(s, hi, lo);
      a.vmhi[b * VDIM + d] = hi;
      a.vmlo[b * VDIM + d] = lo;
    }
  }
  // vproj[b,k,:] = relu(v@Wv^T + bv): 576 tasks of 128 rows x 64 cols
  for (int tt = blk; tt < 576; tt += 256) {
    const int mg = tt % 36, ng = tt / 36;
    const int row = mg * 128 + wv * 16 + m;
    const int bb = row / NOBJ, ko = row - bb * NOBJ;
    const u16 *ar = a.vh + ((long)a.order[bb] * NOBJ + ko) * VDIM + quad * 8;
    const int c0 = ng * 64;
    const u16 *wr = a.Wvh + (long)(c0 + m) * VDIM + quad * 8;
    f32x4 acc[4] = {};
    mmk<4, false>(acc, ar, nullptr, wr, 16L * VDIM, VDIM / 32);
#pragma unroll
    for (int i = 0; i < 4; ++i) {
      const int col = c0 + i * 16 + m;
      const float bvv = a.bv[col];
#pragma unroll
      for (int r = 0; r < 4; ++r) {
        const int grow = mg * 128 + wv * 16 + quad * 4 + r;
        a.vproj16[(long)grow * HID + col] = f2b_rne(fmaxf(acc[i][r] + bvv, 0.f));
      }
    }
  }
  grid.sync();

  //================= P2: gv1 = v_mean @ Wih1_v^T + bih1 =====================
  if (blk < 48) {
    const int c0 = blk * 64;
    const u16 *ah = a.vmhi + (long)(wv * 16 + m) * VDIM + quad * 8;
    const u16 *al = a.vmlo + (long)(wv * 16 + m) * VDIM + quad * 8;
    const u16 *wr = a.Wih1h + (long)(c0 + m) * 4096 + HID + quad * 8;
    f32x4 acc[4] = {};
    mmk<4, true>(acc, ah, al, wr, 16L * 4096, VDIM / 32);
    for (int i = 0; i < 4; ++i) {
      const int col = c0 + i * 16 + m;
      const float bb = a.bih1[col];
      for (int r = 0; r < 4; ++r) {
        const int grow = wv * 16 + quad * 4 + r;
        a.gv1[(long)grow * 3072 + col] = acc[i][r] + bb;
      }
    }
  }
  grid.sync();

  //================= per-step phases =================
  auto phaseA = [&](int t) { // h1n; blocks 0..63, 16 cols each
    if (blk >= 64) return;
    const int p = t & 1, pn = p ^ 1;
    const int c0 = blk * 16;
    const int arow = wv * 16 + m;
    const u16 *h2h = a.h2hi + (long)p * HSZ + (long)arow * HID + quad * 8;
    const u16 *h2l = a.h2lo + (long)p * HSZ + (long)arow * HID + quad * 8;
    const u16 *h1h = a.h1hi + (long)p * HSZ + (long)arow * HID + quad * 8;
    const u16 *h1l = a.h1lo + (long)p * HSZ + (long)arow * HID + quad * 8;
    const long capoff = ((long)a.order[arow] * MAXLEN + t) * EMB + quad * 8;
    f32x4 gi[3] = {}, gh[3] = {};
    mmk<3, true>(gi, h2h, h2l, a.Wih1h + (long)(c0 + m) * 4096 + quad * 8,
                 1024L * 4096, HID / 32);
    mmk<3, true>(gi, a.caph + capoff, a.capl + capoff,
                 a.Wih1h + (long)(c0 + m) * 4096 + 3072 + quad * 8,
                 1024L * 4096, EMB / 32);
    mmk<3, true>(gh, h1h, h1l, a.Whh1h + (long)(c0 + m) * HID + quad * 8,
                 1024L * HID, HID / 32);
    const int col = c0 + m;
    const float br = a.bhh1[col], bz = a.bhh1[HID + col],
                bn = a.bhh1[2 * HID + col];
#pragma unroll
    for (int r = 0; r < 4; ++r) {
      const int grow = wv * 16 + quad * 4 + r;
      const float *gvr = a.gv1 + (long)grow * 3072;
      float ir = gi[0][r] + gvr[col];
      float iz = gi[1][r] + gvr[HID + col];
      float in_ = gi[2][r] + gvr[2 * HID + col];
      float hr = gh[0][r] + br, hz = gh[1][r] + bz, hn = gh[2][r] + bn;
      float rr = sigmoidf_(ir + hr);
      float zz = sigmoidf_(iz + hz);
      float nn = tanhf_(in_ + rr * hn);
      const long io = (long)p * HSZ + (long)grow * HID + col;
      const long iw = (long)pn * HSZ + (long)grow * HID + col;
      float hnew = (1.f - zz) * nn + zz * a.h1f[io];
      a.h1f[iw] = hnew;
      u16 hi, lo;
      split_bf16(hnew, hi, lo);
      a.h1hi[iw] = hi;
      a.h1lo[iw] = lo;
    }
  };

  auto phaseF = [&](int tf, int pb) { // word = h2n@W2^T+b2, blocks 64..220
    const int fb = blk - 64;
    if (fb < 0 || fb > 156) return;
    const int c0 = fb * 64;
    const u16 *xh = a.h2hi + (long)pb * HSZ + (long)(wv * 16 + m) * HID + quad * 8;
    const u16 *xl = a.h2lo + (long)pb * HSZ + (long)(wv * 16 + m) * HID + quad * 8;
    const u16 *wr = a.W2h + (long)(c0 + m) * HID + quad * 8;
    const int nt = (fb == 156) ? 1 : 4;
    f32x4 acc[4] = {};
    if (nt == 4)
      mmk<4, true>(acc, xh, xl, wr, 16L * HID, HID / 32);
    else
      mmk<1, true>(acc, xh, xl, wr, 16L * HID, HID / 32);
    for (int i = 0; i < nt; ++i) {
      const int col = c0 + i * 16 + m;
      const float bb = a.b2[col];
      for (int r = 0; r < 4; ++r) {
        const int grow = wv * 16 + quad * 4 + r;
        const int msk = tf < a.dl[grow];
        float val = acc[i][r] + bb;
        a.out[(long)grow * PRED_STRIDE + (long)tf * NTOK + col] =
            msk ? val : 0.f;
      }
    }
  };

  auto phaseBslot = [&](int t) { // hq (0..15) | gh2 (16..63) | word(t-1)
    const int p = t & 1, pn = p ^ 1;
    if (blk < 16) {
      const int c0 = blk * 64;
      const u16 *xh = a.h1hi + (long)pn * HSZ + (long)(wv * 16 + m) * HID + quad * 8;
      const u16 *xl = a.h1lo + (long)pn * HSZ + (long)(wv * 16 + m) * HID + quad * 8;
      const u16 *wr = a.W1h + (long)(c0 + m) * HID + quad * 8;
      f32x4 acc[4] = {};
      mmk<4, true>(acc, xh, xl, wr, 16L * HID, HID / 32);
      for (int i = 0; i < 4; ++i) {
        const int col = c0 + i * 16 + m;
        const float bb = a.b1[col];
        for (int r = 0; r < 4; ++r) {
          const int grow = wv * 16 + quad * 4 + r;
          u16 hi, lo;
          split_bf16(acc[i][r] + bb, hi, lo);
          a.hqhi[(long)grow * HID + col] = hi;
          a.hqlo[(long)grow * HID + col] = lo;
        }
      }
    } else if (blk < 64) {
      const int c0 = (blk - 16) * 64;
      const u16 *xh = a.h2hi + (long)p * HSZ + (long)(wv * 16 + m) * HID + quad * 8;
      const u16 *xl = a.h2lo + (long)p * HSZ + (long)(wv * 16 + m) * HID + quad * 8;
      const u16 *wr = a.Whh2h + (long)(c0 + m) * HID + quad * 8;
      f32x4 acc[4] = {};
      mmk<4, true>(acc, xh, xl, wr, 16L * HID, HID / 32);
      for (int i = 0; i < 4; ++i) {
        const int col = c0 + i * 16 + m;
        const float bb = a.bhh2[col];
        for (int r = 0; r < 4; ++r) {
          const int grow = wv * 16 + quad * 4 + r;
          a.gh2s[(long)grow * 3072 + col] = acc[i][r] + bb;
        }
      }
    } else if (t > 0) {
      phaseF(t - 1, p);
    }
  };

  auto phaseC = [&]() { // q = relu(hq@Wq^T+bq); blocks 0..15
    if (blk >= 16) return;
    const int c0 = blk * 64;
    const u16 *xh = a.hqhi + (long)(wv * 16 + m) * HID + quad * 8;
    const u16 *xl = a.hqlo + (long)(wv * 16 + m) * HID + quad * 8;
    const u16 *wr = a.Wqh + (long)(c0 + m) * HID + quad * 8;
    f32x4 acc[4] = {};
    mmk<4, true>(acc, xh, xl, wr, 16L * HID, HID / 32);
    for (int i = 0; i < 4; ++i) {
      const int col = c0 + i * 16 + m;
      const float bb = a.bq[col];
      for (int r = 0; r < 4; ++r) {
        const int grow = wv * 16 + quad * 4 + r;
        a.qf[(long)grow * HID + col] = fmaxf(acc[i][r] + bb, 0.f);
      }
    }
  };

  auto phaseD = [&](int t) { // attention per batch row; blocks 0..127
    if (blk >= NB) return;
    const int b = blk;
    const int ob = a.order[b];
    const float *qrow = a.qf + (long)b * HID;
    for (int k = wv; k < NOBJ; k += 8) {
      const u16 *vp = a.vproj16 + ((long)b * NOBJ + k) * HID;
      float s = 0.f;
      for (int d = lane; d < HID; d += 64) s += b2f(vp[d]) * qrow[d] * a.wa[d];
      s = wred_sum(s);
      if (lane == 0) sl[k] = s + a.ba[0];
    }
    __syncthreads();
    if (wv == 0) {
      float x = (lane < NOBJ) ? sl[lane] : -3.0e38f;
      float mx = wred_max(x);
      float e = (lane < NOBJ) ? __expf(x - mx) : 0.f;
      float den = wred_sum(e);
      float att = e / den;
      if (lane < NOBJ) {
        sl[lane] = att;
        const int msk = t < a.dl[b];
        a.out[ALPHA_OFF + (long)b * (MAXLEN * NOBJ) + t * NOBJ + lane] =
            msk ? att : 0.f;
      }
    }
    __syncthreads();
    const u16 *vb = a.vh + (long)ob * NOBJ * VDIM;
    for (int d = tid; d < VDIM; d += 512) {
      float s = 0.f;
#pragma unroll
      for (int k = 0; k < NOBJ; ++k) s += sl[k] * b2f(vb[(long)k * VDIM + d]);
      u16 hi, lo;
      split_bf16(s, hi, lo);
      a.avhi[(long)b * VDIM + d] = hi;
      a.avlo[(long)b * VDIM + d] = lo;
    }
  };

  auto phaseE = [&](int t) { // h2n; blocks 0..63, 16 cols each
    if (blk >= 64) return;
    const int p = t & 1, pn = p ^ 1;
    const int c0 = blk * 16;
    const int arow = wv * 16 + m;
    const u16 *avh = a.avhi + (long)arow * VDIM + quad * 8;
    const u16 *avl = a.avlo + (long)arow * VDIM + quad * 8;
    const u16 *hqh = a.hqhi + (long)arow * HID + quad * 8;
    const u16 *hql = a.hqlo + (long)arow * HID + quad * 8;
    f32x4 gi[3] = {};
    mmk<3, true>(gi, avh, avl, a.Wih2h + (long)(c0 + m) * 3072 + quad * 8,
                 1024L * 3072, VDIM / 32);
    mmk<3, true>(gi, hqh, hql, a.Wih2h + (long)(c0 + m) * 3072 + 2048 + quad * 8,
                 1024L * 3072, HID / 32);
    const int col = c0 + m;
    const float bir = a.bih2[col], biz = a.bih2[HID + col],
                bin = a.bih2[2 * HID + col];
#pragma unroll
    for (int r = 0; r < 4; ++r) {
      const int grow = wv * 16 + quad * 4 + r;
      const float *ghr = a.gh2s + (long)grow * 3072;
      float ir = gi[0][r] + bir, iz = gi[1][r] + biz, in_ = gi[2][r] + bin;
      float hr = ghr[col], hz = ghr[HID + col], hn = ghr[2 * HID + col];
      float rr = sigmoidf_(ir + hr);
      float zz = sigmoidf_(iz + hz);
      float nn = tanhf_(in_ + rr * hn);
      const long io = (long)p * HSZ + (long)grow * HID + col;
      const long iw = (long)pn * HSZ + (long)grow * HID + col;
      float hnew = (1.f - zz) * nn + zz * a.h2f[io];
      a.h2f[iw] = hnew;
      u16 hi, lo;
      split_bf16(hnew, hi, lo);
      a.h2hi[iw] = hi;
      a.h2lo[iw] = lo;
    }
  };

  phaseA(0);
  grid.sync();
  for (int t = 0; t < T_STEPS; ++t) {
    phaseBslot(t);
    grid.sync();
    phaseC();
    grid.sync();
    phaseD(t);
    grid.sync();
    phaseE(t);
    grid.sync();
    if (t < T_STEPS - 1) {
      phaseA(t + 1);
      grid.sync();
    }
  }
  phaseF(T_STEPS - 1, T_STEPS & 1);
}

extern "C" void kernel_launch(void *const *d_in, const int *in_sizes, int n_in,
                              void *d_out, int out_size, void *d_ws,
                              size_t ws_size, hipStream_t stream) {
  Args a;
  a.v = (const float *)d_in[0];
  a.caption = (const float *)d_in[1];
  a.cap_len = (const int *)d_in[2];
  a.Wih1 = (const float *)d_in[3];
  a.Whh1 = (const float *)d_in[4];
  a.bih1 = (const float *)d_in[5];
  a.bhh1 = (const float *)d_in[6];
  a.Wih2 = (const float *)d_in[7];
  a.Whh2 = (const float *)d_in[8];
  a.bih2 = (const float *)d_in[9];
  a.bhh2 = (const float *)d_in[10];
  a.Wv = (const float *)d_in[11];
  a.bv = (const float *)d_in[12];
  a.Wq = (const float *)d_in[13];
  a.bq = (const float *)d_in[14];
  a.wa = (const float *)d_in[15];
  a.ba = (const float *)d_in[16];
  a.W1 = (const float *)d_in[17];
  a.b1 = (const float *)d_in[18];
  a.W2 = (const float *)d_in[19];
  a.b2 = (const float *)d_in[20];
  a.out = (float *)d_out;

  char *w = (char *)d_ws;
  size_t off = 0;
  auto take = [&](size_t bytes) -> void * {
    void *p = w + off;
    off += (bytes + 255) & ~(size_t)255;
    return p;
  };
  a.order = (int *)take(NB * 4);
  a.dl = (int *)take(NB * 4);
  a.Wih1h = (u16 *)take(3072UL * 4096 * 2);
  a.Whh1h = (u16 *)take(3072UL * 1024 * 2);
  a.Wih2h = (u16 *)take(3072UL * 3072 * 2);
  a.Whh2h = (u16 *)take(3072UL * 1024 * 2);
  a.Wvh = (u16 *)take(1024UL * 2048 * 2);
  a.Wqh = (u16 *)take(1024UL * 1024 * 2);
  a.W1h = (u16 *)take(1024UL * 1024 * 2);
  a.W2h = (u16 *)take((size_t)NTOK * 1024 * 2);
  a.vh = (u16 *)take((size_t)NB * NOBJ * VDIM * 2);
  a.caph = (u16 *)take((size_t)NB * MAXLEN * EMB * 2);
  a.capl = (u16 *)take((size_t)NB * MAXLEN * EMB * 2);
  a.vproj16 = (u16 *)take((size_t)NB * NOBJ * HID * 2);
  a.gv1 = (float *)take((size_t)NB * 3072 * 4);
  a.gh2s = (float *)take((size_t)NB * 3072 * 4);
  a.h1f = (float *)take((size_t)2 * HSZ * 4);
  a.h2f = (float *)take((size_t)2 * HSZ * 4);
  a.qf = (float *)take((size_t)HSZ * 4);
  a.h1hi = (u16 *)take((size_t)2 * HSZ * 2);
  a.h1lo = (u16 *)take((size_t)2 * HSZ * 2);
  a.h2hi = (u16 *)take((size_t)2 * HSZ * 2);
  a.h2lo = (u16 *)take((size_t)2 * HSZ * 2);
  a.hqhi = (u16 *)take((size_t)HSZ * 2);
  a.hqlo = (u16 *)take((size_t)HSZ * 2);
  a.avhi = (u16 *)take((size_t)NB * VDIM * 2);
  a.avlo = (u16 *)take((size_t)NB * VDIM * 2);
  a.vmhi = (u16 *)take((size_t)NB * VDIM * 2);
  a.vmlo = (u16 *)take((size_t)NB * VDIM * 2);

  void *kargs[] = {(void *)&a};
  hipLaunchCooperativeKernel((const void *)butd, dim3(256), dim3(512), kargs, 0,
                             stream);
}